// Round 11
// baseline (5342.228 us; speedup 1.0000x reference)
//
#include <hip/hip_runtime.h>
#include <hip/hip_bf16.h>
#include <math.h>

// TS=50, TT=48, B=64, E=H=1024, VIN=VOUT=32000
// out[b][v][t] = logits[t][b][v], shape (64, 32000, 47)

typedef __attribute__((ext_vector_type(8))) short short8;
typedef __attribute__((ext_vector_type(4))) float floatx4;
typedef unsigned short u16;

#define DEV static __device__ __forceinline__

DEV float bf2f(u16 u){ union{unsigned int i; float f;} v; v.i = ((unsigned int)u)<<16; return v.f; }
DEV u16 f2bf(float f){
  union{float f; unsigned int i;} v; v.f = f;
  unsigned int i = v.i;
  return (u16)((i + 0x7fffu + ((i>>16)&1u)) >> 16);
}
DEV float sigm(float x){ return 1.f/(1.f+expf(-x)); }

// ---------------- weight convert: f32 -> single bf16 ----------------------
__global__ __launch_bounds__(256) void cvt2d(const float* __restrict__ src, long sld,
                                             u16* __restrict__ dst, long dld, long cols)
{
  long r = blockIdx.x;
  long c = ((long)blockIdx.y*256 + threadIdx.x)*4;
  if (c >= cols) return;
  const float4 v = *(const float4*)(src + r*sld + c);
  u16* d = dst + r*dld + c;
  d[0]=f2bf(v.x); d[1]=f2bf(v.y); d[2]=f2bf(v.z); d[3]=f2bf(v.w);
}

DEV void split_store(const float4 v, u16* d, u16* e){
  u16 h0=f2bf(v.x), h1=f2bf(v.y), h2=f2bf(v.z), h3=f2bf(v.w);
  d[0]=h0; d[1]=h1; d[2]=h2; d[3]=h3;
  e[0]=f2bf(v.x-bf2f(h0)); e[1]=f2bf(v.y-bf2f(h1));
  e[2]=f2bf(v.z-bf2f(h2)); e[3]=f2bf(v.w-bf2f(h3));
}

// family A: four 4096x1024 (ld 1024) weight splits, z selects
__global__ __launch_bounds__(256) void cvtA(
    const float* s0, const float* s1, const float* s2, const float* s3,
    u16* h0, u16* h1, u16* h2, u16* h3,
    u16* l0, u16* l1, u16* l2, u16* l3)
{
  const float* s; u16* h; u16* l;
  switch (blockIdx.z){
    case 0: s=s0; h=h0; l=l0; break;
    case 1: s=s1; h=h1; l=l1; break;
    case 2: s=s2; h=h2; l=l2; break;
    default: s=s3; h=h3; l=l3; break;
  }
  long r = blockIdx.x; long c = (long)threadIdx.x*4;
  split_store(*(const float4*)(s + r*1024 + c), h + r*1024 + c, l + r*1024 + c);
}

// family B: four 1024-row, 2048-col weight splits with per-slot SOURCE stride
__global__ __launch_bounds__(256) void cvtB(
    const float* s0, long sld0, const float* s1, long sld1,
    const float* s2, long sld2, const float* s3, long sld3,
    u16* h0, u16* h1, u16* h2, u16* h3,
    u16* l0, u16* l1, u16* l2, u16* l3)
{
  const float* s; u16* h; u16* l; long sld;
  switch (blockIdx.z){
    case 0: s=s0; h=h0; l=l0; sld=sld0; break;
    case 1: s=s1; h=h1; l=l1; sld=sld1; break;
    case 2: s=s2; h=h2; l=l2; sld=sld2; break;
    default: s=s3; h=h3; l=l3; sld=sld3; break;
  }
  long r = blockIdx.x;
  long c = ((long)blockIdx.y*256 + threadIdx.x)*4;
  split_store(*(const float4*)(s + r*sld + c), h + r*2048 + c, l + r*2048 + c);
}

// family C: three 1024-col pieces: (src,sld)->(dst,dld)
__global__ __launch_bounds__(256) void cvtC(
    const float* s0, long sld0, u16* h0, u16* l0, long dld0,
    const float* s1, long sld1, u16* h1, u16* l1, long dld1,
    const float* s2, long sld2, u16* h2, u16* l2, long dld2)
{
  const float* s; u16* h; u16* l; long sld, dld;
  switch (blockIdx.z){
    case 0: s=s0; h=h0; l=l0; sld=sld0; dld=dld0; break;
    case 1: s=s1; h=h1; l=l1; sld=sld1; dld=dld1; break;
    default: s=s2; h=h2; l=l2; sld=sld2; dld=dld2; break;
  }
  long r = blockIdx.x; long c = (long)threadIdx.x*4;
  split_store(*(const float4*)(s + r*sld + c), h + r*dld + c, l + r*dld + c);
}

// ---- cell-state convert: c_enc[2][64][1024] f32 -> [64][2048] hi/lo bf16 --
__global__ __launch_bounds__(256) void cvt_cell_split(const float* __restrict__ c_all,
                                                      u16* __restrict__ hi, u16* __restrict__ lo)
{
  int b = blockIdx.x, tid = threadIdx.x;
  for (int k = 0; k < 8; k++){
    int u = tid + k*256;
    int dir = u >> 10, uu = u & 1023;
    float v = c_all[dir*65536 + b*1024 + uu];
    u16 h = f2bf(v);
    hi[b*2048 + u] = h;
    lo[b*2048 + u] = f2bf(v - bf2f(h));
  }
}

__global__ __launch_bounds__(256) void bias_combine(
    const float* a1,const float* a2,float* o1,
    const float* b1,const float* b2,float* o2,
    const float* c1,const float* c2,float* o3,
    const float* battn, float* o4)
{
  int i = blockIdx.x*256 + threadIdx.x;
  if (i < 4096){ o1[i]=a1[i]+a2[i]; o2[i]=b1[i]+b2[i]; o3[i]=c1[i]+c2[i]; }
  if (i < 2048) o4[i] = (i < 1024) ? battn[i] : 0.f;
}

__global__ __launch_bounds__(256) void zero_u32(unsigned int* p, int n){
  int i = blockIdx.x*256 + threadIdx.x;
  if (i < n) p[i] = 0;
}

// embedding gather row r -> table[idx[r]], hi/lo split (E=1024)
__global__ __launch_bounds__(256) void gather_embed_split(const int* __restrict__ idx,
                                                          const float* __restrict__ tab,
                                                          u16* __restrict__ hi, u16* __restrict__ lo)
{
  int r = blockIdx.x, tid = threadIdx.x;
  int tok = idx[r];
  float4 v = ((const float4*)(tab + (long)tok*1024))[tid];
  split_store(v, hi + (long)r*1024 + tid*4, lo + (long)r*1024 + tid*4);
}

// ---------------- 128x128 tile GEMM: Cf = A(M,K) @ B(N,K)^T + bias ---------
// 3-pass split (hh + lh + hl), f32 out
template<int AS, int BS>
__global__ __launch_bounds__(256) void gemm128(
    const u16* __restrict__ Ahi, const u16* __restrict__ Alo, int lda,
    const u16* __restrict__ Bhi, const u16* __restrict__ Blo, int ldb,
    int M, int N, int K,
    const float* __restrict__ bias,
    float* __restrict__ Cf, int ldc)
{
  __shared__ u16 Ash[128][36];
  __shared__ u16 Bsh[128][36];
  __shared__ u16 Asl[AS?128:1][36];
  __shared__ u16 Bsl[BS?128:1][36];
  const int tid = threadIdx.x;
  const int lane = tid & 63;
  const int w = tid >> 6, wm = w >> 1, wn = w & 1;
  const int m0 = blockIdx.x * 128;
  const int n0 = blockIdx.y * 128;

  floatx4 acc[4][4];
  #pragma unroll
  for (int i=0;i<4;i++)
    #pragma unroll
    for (int j=0;j<4;j++) acc[i][j] = (floatx4)0.f;

  const int seg = tid & 3;
  const int rowh = tid >> 2;
  const int nk = K >> 5;
  for (int kk = 0; kk < nk; kk++) {
    int kbase = kk*32 + seg*8;
    #pragma unroll
    for (int p=0;p<2;p++){
      int r = rowh + p*64;
      bool okA = (m0 + r < M);
      int4 va = okA ? *(const int4*)(Ahi + (long)(m0+r)*lda + kbase) : make_int4(0,0,0,0);
      *(int4*)&Ash[r][seg*8] = va;
      if (AS){
        int4 vl = okA ? *(const int4*)(Alo + (long)(m0+r)*lda + kbase) : make_int4(0,0,0,0);
        *(int4*)&Asl[r][seg*8] = vl;
      }
      *(int4*)&Bsh[r][seg*8] = *(const int4*)(Bhi + (long)(n0+r)*ldb + kbase);
      if (BS)
        *(int4*)&Bsl[r][seg*8] = *(const int4*)(Blo + (long)(n0+r)*ldb + kbase);
    }
    __syncthreads();
    short8 ah[4], bh[4], al[4], bl[4];
    #pragma unroll
    for (int i=0;i<4;i++){
      ah[i] = *(const short8*)&Ash[wm*64 + i*16 + (lane&15)][(lane>>4)*8];
      if (AS) al[i] = *(const short8*)&Asl[wm*64 + i*16 + (lane&15)][(lane>>4)*8];
    }
    #pragma unroll
    for (int j=0;j<4;j++){
      bh[j] = *(const short8*)&Bsh[wn*64 + j*16 + (lane&15)][(lane>>4)*8];
      if (BS) bl[j] = *(const short8*)&Bsl[wn*64 + j*16 + (lane&15)][(lane>>4)*8];
    }
    #pragma unroll
    for (int i=0;i<4;i++)
      #pragma unroll
      for (int j=0;j<4;j++){
        acc[i][j] = __builtin_amdgcn_mfma_f32_16x16x32_bf16(ah[i], bh[j], acc[i][j], 0,0,0);
        if (AS) acc[i][j] = __builtin_amdgcn_mfma_f32_16x16x32_bf16(al[i], bh[j], acc[i][j], 0,0,0);
        if (BS) acc[i][j] = __builtin_amdgcn_mfma_f32_16x16x32_bf16(ah[i], bl[j], acc[i][j], 0,0,0);
      }
    __syncthreads();
  }
  const int rb0 = (lane>>4)*4, cf = lane & 15;
  #pragma unroll
  for (int i=0;i<4;i++){
    #pragma unroll
    for (int j=0;j<4;j++){
      int n = n0 + wn*64 + j*16 + cf;
      #pragma unroll
      for (int r=0;r<4;r++){
        int m = m0 + wm*64 + i*16 + rb0 + r;
        if (m >= M) continue;
        Cf[(long)m*ldc + n] = acc[i][j][r] + (bias ? bias[n] : 0.f);
      }
    }
  }
}

// ---------------- small GEMM: M=64 rows (batch), 64-wide N tile ------------
// 3-pass. MODE 0 (hidden init): o1hi/lo[b*2048 + n] = split(v)
//         MODE 1 (cell init):   outF[b*1024+n] = v
template<int MODE>
__global__ __launch_bounds__(256) void gemm64(
    const u16* __restrict__ Ahi, const u16* __restrict__ Alo, int lda,
    const u16* __restrict__ Bhi, const u16* __restrict__ Blo, int ldb,
    int K, const float* __restrict__ bias,
    float* __restrict__ outF,
    u16* __restrict__ o1hi, u16* __restrict__ o1lo)
{
  __shared__ u16 Ash[64][36], Asl[64][36];
  __shared__ u16 Bsh[64][36], Bsl[64][36];
  const int tid = threadIdx.x, lane = tid&63, w = tid>>6;
  const int n0 = blockIdx.x * 64;
  floatx4 acc[4];
  #pragma unroll
  for (int i=0;i<4;i++) acc[i]=(floatx4)0.f;
  const int seg = tid&3, row = tid>>2;
  const int nk = K>>5;
  for (int kk=0; kk<nk; kk++){
    int kbase = kk*32 + seg*8;
    *(int4*)&Ash[row][seg*8] = *(const int4*)(Ahi + (long)row*lda + kbase);
    *(int4*)&Asl[row][seg*8] = *(const int4*)(Alo + (long)row*lda + kbase);
    *(int4*)&Bsh[row][seg*8] = *(const int4*)(Bhi + (long)(n0+row)*ldb + kbase);
    *(int4*)&Bsl[row][seg*8] = *(const int4*)(Blo + (long)(n0+row)*ldb + kbase);
    __syncthreads();
    short8 bh = *(const short8*)&Bsh[w*16 + (lane&15)][(lane>>4)*8];
    short8 bl = *(const short8*)&Bsl[w*16 + (lane&15)][(lane>>4)*8];
    #pragma unroll
    for (int i=0;i<4;i++){
      short8 ah = *(const short8*)&Ash[i*16 + (lane&15)][(lane>>4)*8];
      short8 al = *(const short8*)&Asl[i*16 + (lane&15)][(lane>>4)*8];
      acc[i] = __builtin_amdgcn_mfma_f32_16x16x32_bf16(ah, bh, acc[i], 0,0,0);
      acc[i] = __builtin_amdgcn_mfma_f32_16x16x32_bf16(al, bh, acc[i], 0,0,0);
      acc[i] = __builtin_amdgcn_mfma_f32_16x16x32_bf16(ah, bl, acc[i], 0,0,0);
    }
    __syncthreads();
  }
  const int rb0 = (lane>>4)*4, cf = lane&15;
  int n = n0 + w*16 + cf;
  #pragma unroll
  for (int i=0;i<4;i++){
    #pragma unroll
    for (int r=0;r<4;r++){
      int m = i*16 + rb0 + r;  // batch index
      float v = acc[i][r] + bias[n];
      if (MODE == 0){
        u16 h = f2bf(v), l = f2bf(v - bf2f(h));
        o1hi[m*2048 + n] = h; o1lo[m*2048 + n] = l;
      } else {
        outF[m*1024 + n] = v;
      }
    }
  }
}

// ---------------- encoder LSTM step: no-LDS-staging, XCD-aware -------------
// 256 blocks: b0 = (bx>>7)*32; dir = (bx>>6)&1; u0 = (bx&63)*16. Wave = gate.
// A fragments read directly from global (L1-served; all 4 waves share).
__global__ __launch_bounds__(256) void enc_step(
    int s,
    const u16* __restrict__ hin_hi, const u16* __restrict__ hin_lo,   // [64][2048]
    u16* __restrict__ hout_hi, u16* __restrict__ hout_lo,
    float* __restrict__ c_all,       // [2][64][1024]
    const u16* __restrict__ Whhf_hi, const u16* __restrict__ Whhf_lo,
    const u16* __restrict__ Whhb_hi, const u16* __restrict__ Whhb_lo,
    const float* __restrict__ Gfb,   // [3200][8192] f32
    const float* __restrict__ bias_f, const float* __restrict__ bias_b,
    const int* __restrict__ src_len,
    u16* __restrict__ eo_hi, u16* __restrict__ eo_lo)   // [64][50][2048]
{
  __shared__ float gl[4][32][17];
  const int tid = threadIdx.x, lane = tid&63, w = tid>>6;
  const int b0  = (blockIdx.x >> 7) * 32;
  const int dir = (blockIdx.x >> 6) & 1;
  const int u0  = (blockIdx.x & 63) * 16;
  const u16* Whh_hi = dir ? Whhb_hi : Whhf_hi;
  const u16* Whh_lo = dir ? Whhb_lo : Whhf_lo;
  const float* bias = dir ? bias_b : bias_f;
  const int trow = dir ? (49 - s) : s;

  const int lane15 = lane & 15;
  const int cseg = (lane>>4)*8;
  const u16* a0h = hin_hi + dir*1024 + (long)(b0+lane15)*2048 + cseg;
  const u16* a0l = hin_lo + dir*1024 + (long)(b0+lane15)*2048 + cseg;
  const u16* a1h = a0h + 16*2048;
  const u16* a1l = a0l + 16*2048;
  const int rowb = w*1024 + u0 + lane15;
  const u16* bhp = Whh_hi + (long)rowb*1024 + cseg;
  const u16* blp = Whh_lo + (long)rowb*1024 + cseg;

  floatx4 acc0 = (floatx4)0.f, acc1 = (floatx4)0.f;
  #pragma unroll 4
  for (int kk=0; kk<32; kk++){
    int kbase = kk*32;
    short8 bh = *(const short8*)(bhp + kbase);
    short8 bl = *(const short8*)(blp + kbase);
    short8 ah0 = *(const short8*)(a0h + kbase);
    short8 al0 = *(const short8*)(a0l + kbase);
    short8 ah1 = *(const short8*)(a1h + kbase);
    short8 al1 = *(const short8*)(a1l + kbase);
    acc0 = __builtin_amdgcn_mfma_f32_16x16x32_bf16(ah0, bh, acc0, 0,0,0);
    acc0 = __builtin_amdgcn_mfma_f32_16x16x32_bf16(al0, bh, acc0, 0,0,0);
    acc0 = __builtin_amdgcn_mfma_f32_16x16x32_bf16(ah0, bl, acc0, 0,0,0);
    acc1 = __builtin_amdgcn_mfma_f32_16x16x32_bf16(ah1, bh, acc1, 0,0,0);
    acc1 = __builtin_amdgcn_mfma_f32_16x16x32_bf16(al1, bh, acc1, 0,0,0);
    acc1 = __builtin_amdgcn_mfma_f32_16x16x32_bf16(ah1, bl, acc1, 0,0,0);
  }
  const int rb0 = (lane>>4)*4;
  #pragma unroll
  for (int r=0;r<4;r++){
    gl[w][rb0 + r][lane15]      = acc0[r];
    gl[w][16 + rb0 + r][lane15] = acc1[r];
  }
  __syncthreads();
  for (int k=0;k<2;k++){
    int idx = tid + k*256;
    int bl_ = idx >> 4, u = idx & 15;
    int b = b0 + bl_, uu = u0 + u;
    long grow = (long)(trow*64 + b)*8192 + dir*4096;
    float gi = gl[0][bl_][u] + Gfb[grow +        uu] + bias[uu];
    float gf = gl[1][bl_][u] + Gfb[grow + 1024 + uu] + bias[1024+uu];
    float gg2 = gl[2][bl_][u] + Gfb[grow + 2048 + uu] + bias[2048+uu];
    float go = gl[3][bl_][u] + Gfb[grow + 3072 + uu] + bias[3072+uu];
    float c_old = c_all[dir*65536 + b*1024 + uu];
    float c_new = sigm(gf)*c_old + sigm(gi)*tanhf(gg2);
    float h_new = sigm(go)*tanhf(c_new);
    bool valid = trow < src_len[b];
    if (valid) c_all[dir*65536 + b*1024 + uu] = c_new;
    u16 hh = f2bf(h_new);
    u16 hl = f2bf(h_new - bf2f(hh));
    int hidx = b*2048 + dir*1024 + uu;
    hout_hi[hidx] = valid ? hh : hin_hi[hidx];
    hout_lo[hidx] = valid ? hl : hin_lo[hidx];
    long eidx = (long)(b*50 + trow)*2048 + dir*1024 + uu;
    eo_hi[eidx] = valid ? hh : (u16)0;
    eo_lo[eidx] = valid ? hl : (u16)0;
  }
}

// ---------------- decoder gates step: no-LDS-staging, XCD-aware ------------
// 256 blocks: b0 = (bx>>6)*16; u0 = (bx&63)*16. Wave = gate.
__global__ __launch_bounds__(256) void dec_gates(
    int t,
    const u16* __restrict__ ain_hi, const u16* __restrict__ ain_lo,
    u16* __restrict__ aout_hi, u16* __restrict__ aout_lo,
    float* __restrict__ c_dec,
    const u16* __restrict__ Wcat_hi, const u16* __restrict__ Wcat_lo,
    const float* __restrict__ Gd,       // [3008][4096] f32
    const float* __restrict__ bias_d,
    float* __restrict__ hf32)           // [64][1024]
{
  __shared__ float gl[4][16][17];
  const int tid=threadIdx.x, lane=tid&63, w=tid>>6;
  const int b0 = (blockIdx.x >> 6) * 16;
  const int u0 = (blockIdx.x & 63) * 16;

  const int lane15 = lane & 15;
  const int cseg = (lane>>4)*8;
  const u16* aph = ain_hi + (long)(b0+lane15)*2048 + cseg;
  const u16* apl = ain_lo + (long)(b0+lane15)*2048 + cseg;
  const int rowb = w*1024 + u0 + lane15;
  const u16* bhp = Wcat_hi + (long)rowb*2048 + cseg;
  const u16* blp = Wcat_lo + (long)rowb*2048 + cseg;

  floatx4 acc = (floatx4)0.f;
  #pragma unroll 4
  for (int kk=0; kk<64; kk++){
    int kbase = kk*32;
    short8 bh = *(const short8*)(bhp + kbase);
    short8 bl = *(const short8*)(blp + kbase);
    short8 ah = *(const short8*)(aph + kbase);
    short8 al = *(const short8*)(apl + kbase);
    acc = __builtin_amdgcn_mfma_f32_16x16x32_bf16(ah,bh,acc,0,0,0);
    acc = __builtin_amdgcn_mfma_f32_16x16x32_bf16(al,bh,acc,0,0,0);
    acc = __builtin_amdgcn_mfma_f32_16x16x32_bf16(ah,bl,acc,0,0,0);
  }
  const int rb0=(lane>>4)*4;
  #pragma unroll
  for(int r=0;r<4;r++) gl[w][rb0+r][lane15] = acc[r];
  __syncthreads();
  {
    int bl_ = tid>>4, u = tid&15;
    int b = b0 + bl_, uu = u0 + u;
    long grow = (long)(t*64 + b)*4096;
    float gi = gl[0][bl_][u] + Gd[grow +        uu] + bias_d[uu];
    float gf = gl[1][bl_][u] + Gd[grow + 1024 + uu] + bias_d[1024+uu];
    float gg2 = gl[2][bl_][u] + Gd[grow + 2048 + uu] + bias_d[2048+uu];
    float go = gl[3][bl_][u] + Gd[grow + 3072 + uu] + bias_d[3072+uu];
    float c_old = c_dec[b*1024+uu];
    float c_new = sigm(gf)*c_old + sigm(gi)*tanhf(gg2);
    float h_new = sigm(go)*tanhf(c_new);
    c_dec[b*1024+uu] = c_new;
    u16 hh = f2bf(h_new);
    u16 hl = f2bf(h_new - bf2f(hh));
    aout_hi[b*2048 + uu] = hh;  aout_lo[b*2048 + uu] = hl;
    hf32[b*1024 + uu] = h_new;
  }
}

// ---------------- attention scores+softmax (one block per batch) -----------
__global__ __launch_bounds__(256) void attn_w(
    const float* __restrict__ APf,          // [64*50][2048]: cols 0-1023 attnp
    const float* __restrict__ hf32,         // [64][1024]
    const int* __restrict__ src_len,
    float* __restrict__ wout)               // [64][50]
{
  __shared__ float h_sh[1024];
  __shared__ float sc_sh[50];
  const int tid = threadIdx.x, lane = tid&63, w = tid>>6;
  const int b = blockIdx.x;
  for (int i = tid; i < 1024; i += 256) h_sh[i] = hf32[b*1024 + i];
  __syncthreads();
  for (int tp = w; tp < 50; tp += 4){
    const float* ap = APf + (long)(b*50+tp)*2048;
    float p = 0.f;
    #pragma unroll
    for (int i=0;i<16;i++){ int d = lane + i*64; p += ap[d]*h_sh[d]; }
    #pragma unroll
    for (int off=32; off>0; off>>=1) p += __shfl_down(p, off);
    if (lane==0) sc_sh[tp] = p;
  }
  __syncthreads();
  if (w == 0){
    int len = src_len[b];
    float s = (lane < 50 && lane < len) ? sc_sh[lane] : -3.4e38f;
    float mx = s;
    #pragma unroll
    for (int off=32; off>0; off>>=1) mx = fmaxf(mx, __shfl_xor(mx, off));
    float p = (lane < 50 && lane < len) ? expf(s - mx) : 0.f;
    float sum = p;
    #pragma unroll
    for (int off=32; off>0; off>>=1) sum += __shfl_xor(sum, off);
    if (lane < 50) wout[b*50 + lane] = p / sum;
  }
}

// ---------------- dout step: no-LDS-staging, XCD-aware ---------------------
// b0 = ((bx>>6)&3)*16, n0 = (bx&63)*16. Waves split K=1024 into 4x256.
__global__ __launch_bounds__(256) void dout_step(
    int t,
    const u16* __restrict__ h_hi, const u16* __restrict__ h_lo,   // ac (h half), ld 2048
    const u16* __restrict__ Wch_h, const u16* __restrict__ Wch_l, // [1024][1024]
    const float* __restrict__ APf,      // [64*50][2048]: cols 1024+ = P
    const float* __restrict__ wout,     // [64][50]
    const float* __restrict__ bcomb,
    u16* __restrict__ ac_hi, u16* __restrict__ ac_lo,             // dout half out
    u16* __restrict__ dall_h)
{
  __shared__ float gl[4][16][17];
  const int tid=threadIdx.x, lane=tid&63, w=tid>>6;
  const int b0 = ((blockIdx.x >> 6) & 3) * 16;
  const int n0 = (blockIdx.x & 63) * 16;

  const int lane15 = lane & 15;
  const int cseg = (lane>>4)*8;
  const u16* aph = h_hi + (long)(b0+lane15)*2048 + w*256 + cseg;
  const u16* apl = h_lo + (long)(b0+lane15)*2048 + w*256 + cseg;
  const u16* bph = Wch_h + (long)(n0+lane15)*1024 + w*256 + cseg;
  const u16* bpl = Wch_l + (long)(n0+lane15)*1024 + w*256 + cseg;

  floatx4 acc = (floatx4)0.f;
  #pragma unroll
  for (int kk=0; kk<8; kk++){
    int kbase = kk*32;
    short8 ah = *(const short8*)(aph + kbase);
    short8 al = *(const short8*)(apl + kbase);
    short8 bh = *(const short8*)(bph + kbase);
    short8 bl = *(const short8*)(bpl + kbase);
    acc = __builtin_amdgcn_mfma_f32_16x16x32_bf16(ah,bh,acc,0,0,0);
    acc = __builtin_amdgcn_mfma_f32_16x16x32_bf16(al,bh,acc,0,0,0);
    acc = __builtin_amdgcn_mfma_f32_16x16x32_bf16(ah,bl,acc,0,0,0);
  }
  const int rb0=(lane>>4)*4;
  #pragma unroll
  for(int rr=0;rr<4;rr++) gl[w][rb0+rr][lane15] = acc[rr];
  __syncthreads();
  {
    int bl_ = tid>>4, nl = tid&15;
    int b = b0 + bl_, nn = n0 + nl;
    float v = gl[0][bl_][nl]+gl[1][bl_][nl]+gl[2][bl_][nl]+gl[3][bl_][nl] + bcomb[nn];
    const float* wp = wout + b*50;
    const float* Pp = APf + (long)(b*50)*2048 + 1024 + nn;
    for (int tp=0; tp<50; tp++) v += wp[tp] * Pp[(long)tp*2048];
    u16 h = f2bf(v), l = f2bf(v - bf2f(h));
    ac_hi[b*2048 + 1024 + nn] = h;  ac_lo[b*2048 + 1024 + nn] = l;
    float rv = v > 0.f ? v : 0.f;
    dall_h[(long)(b*47 + t)*1024 + nn] = f2bf(rv);
  }
}

// ---------------- logits: out_b[v][t] = Wout @ dall_b^T + bout -------------
// XCD-partitioned grid (8, 512): x = XCD slot; y = vtile-local*32 + bpair.
// 2 batch elements per block: staged Wout tile reused for 2 D-tiles
// (halves Wout read demand, doubles MFMA per LDS stage).
__global__ __launch_bounds__(256) void logits_gemm(
    const u16* __restrict__ Wout_bf,                // [32000][1024]
    const u16* __restrict__ dall_h,                 // [3009][1024]
    const float* __restrict__ bout,
    float* __restrict__ out)                        // [64][32000][47]
{
  const int x = blockIdx.x;                 // 0..7
  const int y = blockIdx.y;                 // 0..511
  const int cnt = (x < 5) ? 16 : 15;        // vtiles for this XCD (125 total)
  if (y >= cnt*32) return;
  const int vt = ((x < 5) ? x*16 : 80 + (x-5)*15) + (y >> 5);
  const int b0 = (y & 31)*2;
  const int v0 = vt * 256;

  __shared__ u16 Wsh[256][36];
  __shared__ u16 Dh[2][48][36];
  const int tid = threadIdx.x, lane = tid&63, w = tid>>6;
  floatx4 acc[2][4][3];
  #pragma unroll
  for (int bb=0;bb<2;bb++)
    #pragma unroll
    for (int i=0;i<4;i++)
      #pragma unroll
      for (int j=0;j<3;j++) acc[bb][i][j]=(floatx4)0.f;
  const int lrow = tid>>1, lseg = tid&1;
  for (int kk=0; kk<32; kk++){
    int kb = kk*32;
    #pragma unroll
    for (int p=0;p<2;p++){
      int row = lrow + p*128;
      const u16* src = Wout_bf + (long)(v0+row)*1024 + kb + lseg*16;
      *(int4*)&Wsh[row][lseg*16]     = *(const int4*)(src);
      *(int4*)&Wsh[row][lseg*16 + 8] = *(const int4*)(src + 8);
    }
    if (tid < 192){
      int bb = tid/96, t2 = tid - bb*96;
      int row = t2>>1, sg = t2&1;
      long a = (long)((b0+bb)*47+row)*1024 + kb + sg*16;
      *(int4*)&Dh[bb][row][sg*16]     = *(const int4*)(dall_h + a);
      *(int4*)&Dh[bb][row][sg*16 + 8] = *(const int4*)(dall_h + a + 8);
    }
    __syncthreads();
    short8 av[4];
    #pragma unroll
    for (int i=0;i<4;i++)
      av[i] = *(const short8*)&Wsh[w*64 + i*16 + (lane&15)][(lane>>4)*8];
    #pragma unroll
    for (int j=0;j<3;j++){
      #pragma unroll
      for (int bb=0;bb<2;bb++){
        short8 bh = *(const short8*)&Dh[bb][j*16 + (lane&15)][(lane>>4)*8];
        #pragma unroll
        for (int i=0;i<4;i++)
          acc[bb][i][j] = __builtin_amdgcn_mfma_f32_16x16x32_bf16(av[i], bh, acc[bb][i][j], 0,0,0);
      }
    }
    __syncthreads();
  }
  const int rb0=(lane>>4)*4, cf=lane&15;
  #pragma unroll
  for (int bb=0;bb<2;bb++){
    #pragma unroll
    for (int i=0;i<4;i++){
      #pragma unroll
      for (int j=0;j<3;j++){
        int tt = j*16 + cf;
        if (tt >= 47) continue;
        #pragma unroll
        for (int r=0;r<4;r++){
          int v = v0 + w*64 + i*16 + rb0 + r;
          out[(long)(b0+bb)*1504000 + (long)v*47 + tt] = acc[bb][i][j][r] + bout[v];
        }
      }
    }
  }
}

// ===========================================================================
extern "C" void kernel_launch(void* const* d_in, const int* in_sizes, int n_in,
                              void* d_out, int out_size, void* d_ws, size_t ws_size,
                              hipStream_t stream)
{
  (void)in_sizes; (void)n_in; (void)out_size; (void)ws_size;
  const int*   src     = (const int*)d_in[0];
  const int*   src_len = (const int*)d_in[1];
  const int*   trg     = (const int*)d_in[2];
  const float* enc_emb = (const float*)d_in[3];
  const float* Wih_f   = (const float*)d_in[4];
  const float* Whh_f   = (const float*)d_in[5];
  const float* bih_f   = (const float*)d_in[6];
  const float* bhh_f   = (const float*)d_in[7];
  const float* Wih_b   = (const float*)d_in[8];
  const float* Whh_b   = (const float*)d_in[9];
  const float* bih_b   = (const float*)d_in[10];
  const float* bhh_b   = (const float*)d_in[11];
  const float* Wfch    = (const float*)d_in[12];
  const float* bfch    = (const float*)d_in[13];
  const float* Wfcc    = (const float*)d_in[14];
  const float* bfcc    = (const float*)d_in[15];
  const float* dec_emb = (const float*)d_in[16];
  const float* Wih_d   = (const float*)d_in[17];
  const float* Whh_d   = (const float*)d_in[18];
  const float* bih_d   = (const float*)d_in[19];
  const float* bhh_d   = (const float*)d_in[20];
  const float* Wattn   = (const float*)d_in[21];
  const float* battn   = (const float*)d_in[22];
  const float* Wcomb   = (const float*)d_in[23];
  const float* bcomb   = (const float*)d_in[24];
  const float* Wout    = (const float*)d_in[25];
  const float* bout    = (const float*)d_in[26];
  float* out = (float*)d_out;

  size_t off = 0;
  auto alloc = [&](size_t bytes)->void*{
    void* p = (char*)d_ws + off; off += (bytes + 255) & ~(size_t)255; return p; };

  // combined encoder input-proj weights: rows 0-4095 Wih_f, 4096-8191 Wih_b
  u16* Wenc_h = (u16*)alloc((size_t)8192*1024*2);  u16* Wenc_l = (u16*)alloc((size_t)8192*1024*2);
  u16* Whhf_h = (u16*)alloc((size_t)4096*1024*2);  u16* Whhf_l = (u16*)alloc((size_t)4096*1024*2);
  u16* Whhb_h = (u16*)alloc((size_t)4096*1024*2);  u16* Whhb_l = (u16*)alloc((size_t)4096*1024*2);
  u16* WihdA_h= (u16*)alloc((size_t)4096*1024*2);  u16* WihdA_l= (u16*)alloc((size_t)4096*1024*2);
  u16* Wcat_h = (u16*)alloc((size_t)4096*2048*2);  u16* Wcat_l = (u16*)alloc((size_t)4096*2048*2);
  u16* Wfch_h = (u16*)alloc((size_t)1024*2048*2);  u16* Wfch_l = (u16*)alloc((size_t)1024*2048*2);
  u16* Wfcc_h = (u16*)alloc((size_t)1024*2048*2);  u16* Wfcc_l = (u16*)alloc((size_t)1024*2048*2);
  // combined attn/P weights: rows 0-1023 Wattn, 1024-2047 Wcomb[:, :2048]
  u16* Wap_h  = (u16*)alloc((size_t)2048*2048*2);  u16* Wap_l  = (u16*)alloc((size_t)2048*2048*2);
  u16* Wch_h  = (u16*)alloc((size_t)1024*1024*2);  u16* Wch_l  = (u16*)alloc((size_t)1024*1024*2);
  u16* Wout_bf =(u16*)alloc((size_t)32000*1024*2);
  u16* embx_h = (u16*)alloc((size_t)3200*1024*2);  u16* embx_l = (u16*)alloc((size_t)3200*1024*2);
  u16* dembx_h= (u16*)alloc((size_t)3008*1024*2);  u16* dembx_l= (u16*)alloc((size_t)3008*1024*2);
  float* Gfb  = (float*)alloc((size_t)3200*8192*4);
  float* Gd   = (float*)alloc((size_t)3008*4096*4);
  u16* eo_h  = (u16*)alloc((size_t)3200*2048*2);
  u16* eo_l  = (u16*)alloc((size_t)3200*2048*2);
  u16* h0_h  = (u16*)alloc((size_t)64*2048*2);  u16* h0_l  = (u16*)alloc((size_t)64*2048*2);
  u16* h1_h  = (u16*)alloc((size_t)64*2048*2);  u16* h1_l  = (u16*)alloc((size_t)64*2048*2);
  u16* cfin_h= (u16*)alloc((size_t)64*2048*2);  u16* cfin_l= (u16*)alloc((size_t)64*2048*2);
  u16* ac0_h = (u16*)alloc((size_t)64*2048*2);  u16* ac0_l = (u16*)alloc((size_t)64*2048*2);
  u16* ac1_h = (u16*)alloc((size_t)64*2048*2);  u16* ac1_l = (u16*)alloc((size_t)64*2048*2);
  u16* dall_h= (u16*)alloc((size_t)3009*1024*2);
  float* APf   = (float*)alloc((size_t)3200*2048*4);
  float* c_enc = (float*)alloc((size_t)2*64*1024*4);
  float* c_dec = (float*)alloc((size_t)64*1024*4);
  float* hf32  = (float*)alloc((size_t)64*1024*4);
  float* wout  = (float*)alloc((size_t)64*50*4);
  float* bias_f = (float*)alloc(4096*4);
  float* bias_b = (float*)alloc(4096*4);
  float* bias_d = (float*)alloc(4096*4);
  float* bias_ap= (float*)alloc(2048*4);

  // --- weight conversion (fused families) ---
  cvtA<<<dim3(4096,1,4),256,0,stream>>>(Wih_f, Wih_b, Whh_f, Whh_b,
                                        Wenc_h, Wenc_h + (size_t)4096*1024, Whhf_h, Whhb_h,
                                        Wenc_l, Wenc_l + (size_t)4096*1024, Whhf_l, Whhb_l);
  cvtB<<<dim3(1024,2,4),256,0,stream>>>(Wfch, 2048, Wfcc, 2048, Wattn, 2048, Wcomb, 3072,
                                        Wfch_h, Wfcc_h, Wap_h, Wap_h + (size_t)1024*2048,
                                        Wfch_l, Wfcc_l, Wap_l, Wap_l + (size_t)1024*2048);
  cvtC<<<dim3(4096,1,3),256,0,stream>>>(Wih_d, 2048, WihdA_h, WihdA_l, 1024,
                                        Whh_d, 1024, Wcat_h, Wcat_l, 2048,
                                        Wih_d + 1024, 2048, Wcat_h + 1024, Wcat_l + 1024, 2048);
  cvtC<<<dim3(1024,1,1),256,0,stream>>>(Wcomb + 2048, 3072, Wch_h, Wch_l, 1024,
                                        Wcomb + 2048, 3072, Wch_h, Wch_l, 1024,
                                        Wcomb + 2048, 3072, Wch_h, Wch_l, 1024);
  cvt2d<<<dim3(32000,1),256,0,stream>>>(Wout, 1024, Wout_bf, 1024, 1024);
  bias_combine<<<16,256,0,stream>>>(bih_f,bhh_f,bias_f, bih_b,bhh_b,bias_b, bih_d,bhh_d,bias_d, battn,bias_ap);

  // --- embedding gathers (split) ---
  gather_embed_split<<<3200,256,0,stream>>>(src, enc_emb, embx_h, embx_l);
  gather_embed_split<<<3008,256,0,stream>>>(trg, dec_emb, dembx_h, dembx_l);

  // --- zero-init recurrent state ---
  zero_u32<<<256,256,0,stream>>>((unsigned int*)h0_h, 65536);
  zero_u32<<<256,256,0,stream>>>((unsigned int*)h0_l, 65536);
  zero_u32<<<256,256,0,stream>>>((unsigned int*)ac0_h, 65536);
  zero_u32<<<256,256,0,stream>>>((unsigned int*)ac0_l, 65536);
  zero_u32<<<512,256,0,stream>>>((unsigned int*)c_enc, 131072);

  // --- input projections (3-pass split, bias-free, f32 out) ---
  gemm128<1,1><<<dim3(25,64),256,0,stream>>>(embx_h, embx_l, 1024, Wenc_h, Wenc_l, 1024, 3200, 8192, 1024, nullptr, Gfb, 8192);
  gemm128<1,1><<<dim3(24,32),256,0,stream>>>(dembx_h, dembx_l, 1024, WihdA_h, WihdA_l, 1024, 3008, 4096, 1024, nullptr, Gd, 4096);

  // --- encoder scan (per-step launches) ---
  u16* hh_[2] = {h0_h, h1_h};
  u16* hl_[2] = {h0_l, h1_l};
  for (int s=0; s<50; s++)
    enc_step<<<256,256,0,stream>>>(s, hh_[s&1], hl_[s&1], hh_[(s+1)&1], hl_[(s+1)&1], c_enc,
                                   Whhf_h, Whhf_l, Whhb_h, Whhb_l, Gfb, bias_f, bias_b, src_len, eo_h, eo_l);

  // --- final cell states -> split bf16 ---
  cvt_cell_split<<<64,256,0,stream>>>(c_enc, cfin_h, cfin_l);

  // --- combined attn_proj + P (f32 out, ld 2048) ---
  gemm128<1,1><<<dim3(25,16),256,0,stream>>>(eo_h, eo_l, 2048, Wap_h, Wap_l, 2048, 3200, 2048, 2048, bias_ap, APf, 2048);

  // --- decoder init ---
  gemm64<0><<<16,256,0,stream>>>(h0_h, h0_l, 2048, Wfch_h, Wfch_l, 2048, 2048, bfch, nullptr, ac0_h, ac0_l);
  gemm64<1><<<16,256,0,stream>>>(cfin_h, cfin_l, 2048, Wfcc_h, Wfcc_l, 2048, 2048, bfcc, c_dec, nullptr, nullptr);

  // --- decoder scan (per-step launches) ---
  u16* ah_[2] = {ac0_h, ac1_h};
  u16* al_[2] = {ac0_l, ac1_l};
  for (int t=0; t<47; t++){
    int cur = t&1, nxt = (t+1)&1;
    dec_gates<<<256,256,0,stream>>>(t, ah_[cur], al_[cur], ah_[nxt], al_[nxt], c_dec,
                                    Wcat_h, Wcat_l, Gd, bias_d, hf32);
    attn_w<<<64,256,0,stream>>>(APf, hf32, src_len, wout);
    dout_step<<<256,256,0,stream>>>(t, ah_[nxt], al_[nxt], Wch_h, Wch_l, APf, wout, bcomb,
                                    ah_[nxt], al_[nxt], dall_h);
  }

  // --- output projection, XCD-partitioned, 2 b per block ---
  logits_gemm<<<dim3(8,512),256,0,stream>>>(Wout_bf, dall_h, bout, out);
}

// Round 12
// 4257.970 us; speedup vs baseline: 1.2546x; 1.2546x over previous
//
#include <hip/hip_runtime.h>
#include <hip/hip_bf16.h>
#include <math.h>

// TS=50, TT=48, B=64, E=H=1024, VIN=VOUT=32000
// out[b][v][t] = logits[t][b][v], shape (64, 32000, 47)

typedef __attribute__((ext_vector_type(8))) short short8;
typedef __attribute__((ext_vector_type(4))) float floatx4;
typedef unsigned short u16;

#define DEV static __device__ __forceinline__

DEV float bf2f(u16 u){ union{unsigned int i; float f;} v; v.i = ((unsigned int)u)<<16; return v.f; }
DEV u16 f2bf(float f){
  union{float f; unsigned int i;} v; v.f = f;
  unsigned int i = v.i;
  return (u16)((i + 0x7fffu + ((i>>16)&1u)) >> 16);
}
DEV float sigm(float x){ return 1.f/(1.f+expf(-x)); }

// ---------------- weight convert: f32 -> single bf16 ----------------------
__global__ __launch_bounds__(256) void cvt2d(const float* __restrict__ src, long sld,
                                             u16* __restrict__ dst, long dld, long cols)
{
  long r = blockIdx.x;
  long c = ((long)blockIdx.y*256 + threadIdx.x)*4;
  if (c >= cols) return;
  const float4 v = *(const float4*)(src + r*sld + c);
  u16* d = dst + r*dld + c;
  d[0]=f2bf(v.x); d[1]=f2bf(v.y); d[2]=f2bf(v.z); d[3]=f2bf(v.w);
}

DEV void split_store(const float4 v, u16* d, u16* e){
  u16 h0=f2bf(v.x), h1=f2bf(v.y), h2=f2bf(v.z), h3=f2bf(v.w);
  d[0]=h0; d[1]=h1; d[2]=h2; d[3]=h3;
  e[0]=f2bf(v.x-bf2f(h0)); e[1]=f2bf(v.y-bf2f(h1));
  e[2]=f2bf(v.z-bf2f(h2)); e[3]=f2bf(v.w-bf2f(h3));
}

// family A: four 4096x1024 (ld 1024) weight splits, z selects
__global__ __launch_bounds__(256) void cvtA(
    const float* s0, const float* s1, const float* s2, const float* s3,
    u16* h0, u16* h1, u16* h2, u16* h3,
    u16* l0, u16* l1, u16* l2, u16* l3)
{
  const float* s; u16* h; u16* l;
  switch (blockIdx.z){
    case 0: s=s0; h=h0; l=l0; break;
    case 1: s=s1; h=h1; l=l1; break;
    case 2: s=s2; h=h2; l=l2; break;
    default: s=s3; h=h3; l=l3; break;
  }
  long r = blockIdx.x; long c = (long)threadIdx.x*4;
  split_store(*(const float4*)(s + r*1024 + c), h + r*1024 + c, l + r*1024 + c);
}

// family B: four 1024-row, 2048-col weight splits with per-slot SOURCE stride
__global__ __launch_bounds__(256) void cvtB(
    const float* s0, long sld0, const float* s1, long sld1,
    const float* s2, long sld2, const float* s3, long sld3,
    u16* h0, u16* h1, u16* h2, u16* h3,
    u16* l0, u16* l1, u16* l2, u16* l3)
{
  const float* s; u16* h; u16* l; long sld;
  switch (blockIdx.z){
    case 0: s=s0; h=h0; l=l0; sld=sld0; break;
    case 1: s=s1; h=h1; l=l1; sld=sld1; break;
    case 2: s=s2; h=h2; l=l2; sld=sld2; break;
    default: s=s3; h=h3; l=l3; sld=sld3; break;
  }
  long r = blockIdx.x;
  long c = ((long)blockIdx.y*256 + threadIdx.x)*4;
  split_store(*(const float4*)(s + r*sld + c), h + r*2048 + c, l + r*2048 + c);
}

// family C: three 1024-col pieces: (src,sld)->(dst,dld)
__global__ __launch_bounds__(256) void cvtC(
    const float* s0, long sld0, u16* h0, u16* l0, long dld0,
    const float* s1, long sld1, u16* h1, u16* l1, long dld1,
    const float* s2, long sld2, u16* h2, u16* l2, long dld2)
{
  const float* s; u16* h; u16* l; long sld, dld;
  switch (blockIdx.z){
    case 0: s=s0; h=h0; l=l0; sld=sld0; dld=dld0; break;
    case 1: s=s1; h=h1; l=l1; sld=sld1; dld=dld1; break;
    default: s=s2; h=h2; l=l2; sld=sld2; dld=dld2; break;
  }
  long r = blockIdx.x; long c = (long)threadIdx.x*4;
  split_store(*(const float4*)(s + r*sld + c), h + r*dld + c, l + r*dld + c);
}

// ---- cell-state convert: c_enc[2][64][1024] f32 -> [64][2048] hi/lo bf16 --
__global__ __launch_bounds__(256) void cvt_cell_split(const float* __restrict__ c_all,
                                                      u16* __restrict__ hi, u16* __restrict__ lo)
{
  int b = blockIdx.x, tid = threadIdx.x;
  for (int k = 0; k < 8; k++){
    int u = tid + k*256;
    int dir = u >> 10, uu = u & 1023;
    float v = c_all[dir*65536 + b*1024 + uu];
    u16 h = f2bf(v);
    hi[b*2048 + u] = h;
    lo[b*2048 + u] = f2bf(v - bf2f(h));
  }
}

__global__ __launch_bounds__(256) void bias_combine(
    const float* a1,const float* a2,float* o1,
    const float* b1,const float* b2,float* o2,
    const float* c1,const float* c2,float* o3,
    const float* battn, float* o4)
{
  int i = blockIdx.x*256 + threadIdx.x;
  if (i < 4096){ o1[i]=a1[i]+a2[i]; o2[i]=b1[i]+b2[i]; o3[i]=c1[i]+c2[i]; }
  if (i < 2048) o4[i] = (i < 1024) ? battn[i] : 0.f;
}

__global__ __launch_bounds__(256) void zero_u32(unsigned int* p, int n){
  int i = blockIdx.x*256 + threadIdx.x;
  if (i < n) p[i] = 0;
}

// embedding gather row r -> table[idx[r]], hi/lo split (E=1024)
__global__ __launch_bounds__(256) void gather_embed_split(const int* __restrict__ idx,
                                                          const float* __restrict__ tab,
                                                          u16* __restrict__ hi, u16* __restrict__ lo)
{
  int r = blockIdx.x, tid = threadIdx.x;
  int tok = idx[r];
  float4 v = ((const float4*)(tab + (long)tok*1024))[tid];
  split_store(v, hi + (long)r*1024 + tid*4, lo + (long)r*1024 + tid*4);
}

// ---------------- 128x128 tile GEMM: Cf = A(M,K) @ B(N,K)^T + bias ---------
// 3-pass split (hh + lh + hl), f32 out
template<int AS, int BS>
__global__ __launch_bounds__(256) void gemm128(
    const u16* __restrict__ Ahi, const u16* __restrict__ Alo, int lda,
    const u16* __restrict__ Bhi, const u16* __restrict__ Blo, int ldb,
    int M, int N, int K,
    const float* __restrict__ bias,
    float* __restrict__ Cf, int ldc)
{
  __shared__ u16 Ash[128][36];
  __shared__ u16 Bsh[128][36];
  __shared__ u16 Asl[AS?128:1][36];
  __shared__ u16 Bsl[BS?128:1][36];
  const int tid = threadIdx.x;
  const int lane = tid & 63;
  const int w = tid >> 6, wm = w >> 1, wn = w & 1;
  const int m0 = blockIdx.x * 128;
  const int n0 = blockIdx.y * 128;

  floatx4 acc[4][4];
  #pragma unroll
  for (int i=0;i<4;i++)
    #pragma unroll
    for (int j=0;j<4;j++) acc[i][j] = (floatx4)0.f;

  const int seg = tid & 3;
  const int rowh = tid >> 2;
  const int nk = K >> 5;
  for (int kk = 0; kk < nk; kk++) {
    int kbase = kk*32 + seg*8;
    #pragma unroll
    for (int p=0;p<2;p++){
      int r = rowh + p*64;
      bool okA = (m0 + r < M);
      int4 va = okA ? *(const int4*)(Ahi + (long)(m0+r)*lda + kbase) : make_int4(0,0,0,0);
      *(int4*)&Ash[r][seg*8] = va;
      if (AS){
        int4 vl = okA ? *(const int4*)(Alo + (long)(m0+r)*lda + kbase) : make_int4(0,0,0,0);
        *(int4*)&Asl[r][seg*8] = vl;
      }
      *(int4*)&Bsh[r][seg*8] = *(const int4*)(Bhi + (long)(n0+r)*ldb + kbase);
      if (BS)
        *(int4*)&Bsl[r][seg*8] = *(const int4*)(Blo + (long)(n0+r)*ldb + kbase);
    }
    __syncthreads();
    short8 ah[4], bh[4], al[4], bl[4];
    #pragma unroll
    for (int i=0;i<4;i++){
      ah[i] = *(const short8*)&Ash[wm*64 + i*16 + (lane&15)][(lane>>4)*8];
      if (AS) al[i] = *(const short8*)&Asl[wm*64 + i*16 + (lane&15)][(lane>>4)*8];
    }
    #pragma unroll
    for (int j=0;j<4;j++){
      bh[j] = *(const short8*)&Bsh[wn*64 + j*16 + (lane&15)][(lane>>4)*8];
      if (BS) bl[j] = *(const short8*)&Bsl[wn*64 + j*16 + (lane&15)][(lane>>4)*8];
    }
    #pragma unroll
    for (int i=0;i<4;i++)
      #pragma unroll
      for (int j=0;j<4;j++){
        acc[i][j] = __builtin_amdgcn_mfma_f32_16x16x32_bf16(ah[i], bh[j], acc[i][j], 0,0,0);
        if (AS) acc[i][j] = __builtin_amdgcn_mfma_f32_16x16x32_bf16(al[i], bh[j], acc[i][j], 0,0,0);
        if (BS) acc[i][j] = __builtin_amdgcn_mfma_f32_16x16x32_bf16(ah[i], bl[j], acc[i][j], 0,0,0);
      }
    __syncthreads();
  }
  const int rb0 = (lane>>4)*4, cf = lane & 15;
  #pragma unroll
  for (int i=0;i<4;i++){
    #pragma unroll
    for (int j=0;j<4;j++){
      int n = n0 + wn*64 + j*16 + cf;
      #pragma unroll
      for (int r=0;r<4;r++){
        int m = m0 + wm*64 + i*16 + rb0 + r;
        if (m >= M) continue;
        Cf[(long)m*ldc + n] = acc[i][j][r] + (bias ? bias[n] : 0.f);
      }
    }
  }
}

// ---------------- small GEMM: M=64 rows (batch), 64-wide N tile ------------
// 3-pass. MODE 0 (hidden init): o1hi/lo[b*2048 + n] = split(v)
//         MODE 1 (cell init):   outF[b*1024+n] = v
template<int MODE>
__global__ __launch_bounds__(256) void gemm64(
    const u16* __restrict__ Ahi, const u16* __restrict__ Alo, int lda,
    const u16* __restrict__ Bhi, const u16* __restrict__ Blo, int ldb,
    int K, const float* __restrict__ bias,
    float* __restrict__ outF,
    u16* __restrict__ o1hi, u16* __restrict__ o1lo)
{
  __shared__ u16 Ash[64][36], Asl[64][36];
  __shared__ u16 Bsh[64][36], Bsl[64][36];
  const int tid = threadIdx.x, lane = tid&63, w = tid>>6;
  const int n0 = blockIdx.x * 64;
  floatx4 acc[4];
  #pragma unroll
  for (int i=0;i<4;i++) acc[i]=(floatx4)0.f;
  const int seg = tid&3, row = tid>>2;
  const int nk = K>>5;
  for (int kk=0; kk<nk; kk++){
    int kbase = kk*32 + seg*8;
    *(int4*)&Ash[row][seg*8] = *(const int4*)(Ahi + (long)row*lda + kbase);
    *(int4*)&Asl[row][seg*8] = *(const int4*)(Alo + (long)row*lda + kbase);
    *(int4*)&Bsh[row][seg*8] = *(const int4*)(Bhi + (long)(n0+row)*ldb + kbase);
    *(int4*)&Bsl[row][seg*8] = *(const int4*)(Blo + (long)(n0+row)*ldb + kbase);
    __syncthreads();
    short8 bh = *(const short8*)&Bsh[w*16 + (lane&15)][(lane>>4)*8];
    short8 bl = *(const short8*)&Bsl[w*16 + (lane&15)][(lane>>4)*8];
    #pragma unroll
    for (int i=0;i<4;i++){
      short8 ah = *(const short8*)&Ash[i*16 + (lane&15)][(lane>>4)*8];
      short8 al = *(const short8*)&Asl[i*16 + (lane&15)][(lane>>4)*8];
      acc[i] = __builtin_amdgcn_mfma_f32_16x16x32_bf16(ah, bh, acc[i], 0,0,0);
      acc[i] = __builtin_amdgcn_mfma_f32_16x16x32_bf16(al, bh, acc[i], 0,0,0);
      acc[i] = __builtin_amdgcn_mfma_f32_16x16x32_bf16(ah, bl, acc[i], 0,0,0);
    }
    __syncthreads();
  }
  const int rb0 = (lane>>4)*4, cf = lane&15;
  int n = n0 + w*16 + cf;
  #pragma unroll
  for (int i=0;i<4;i++){
    #pragma unroll
    for (int r=0;r<4;r++){
      int m = i*16 + rb0 + r;  // batch index
      float v = acc[i][r] + bias[n];
      if (MODE == 0){
        u16 h = f2bf(v), l = f2bf(v - bf2f(h));
        o1hi[m*2048 + n] = h; o1lo[m*2048 + n] = l;
      } else {
        outF[m*1024 + n] = v;
      }
    }
  }
}

// ---------------- encoder LSTM step: 512-thread, staged A, dual-chain ------
// grid 256: b0 = (bx>>7)*32; dir = (bx>>6)&1; u0 = (bx&63)*16.
// 8 waves (2/SIMD): wave = (gate g = w&3, row-half rh = (w>>2)*16).
// Dual accumulator chains (even/odd kk) cut the MFMA critical path to 48.
__global__ __launch_bounds__(512) void enc_step(
    int s,
    const u16* __restrict__ hin_hi, const u16* __restrict__ hin_lo,   // [64][2048]
    u16* __restrict__ hout_hi, u16* __restrict__ hout_lo,
    float* __restrict__ c_all,       // [2][64][1024]
    const u16* __restrict__ Whhf_hi, const u16* __restrict__ Whhf_lo,
    const u16* __restrict__ Whhb_hi, const u16* __restrict__ Whhb_lo,
    const float* __restrict__ Gfb,   // [3200][8192] f32
    const float* __restrict__ bias_f, const float* __restrict__ bias_b,
    const int* __restrict__ src_len,
    u16* __restrict__ eo_hi, u16* __restrict__ eo_lo)   // [64][50][2048]
{
  __shared__ u16 Ah[32][1032], Al[32][1032];   // pad -> 2-way bank alias (free)
  __shared__ float gl[4][32][17];
  const int tid = threadIdx.x, lane = tid&63, w = tid>>6;  // w 0..7
  const int b0  = (blockIdx.x >> 7) * 32;
  const int dir = (blockIdx.x >> 6) & 1;
  const int u0  = (blockIdx.x & 63) * 16;
  const u16* Whh_hi = dir ? Whhb_hi : Whhf_hi;
  const u16* Whh_lo = dir ? Whhb_lo : Whhf_lo;
  const float* bias = dir ? bias_b : bias_f;
  const int trow = dir ? (49 - s) : s;

  // stage A: 512 threads, row = tid>>4 (0..31), c0 = (tid&15)*8, 8 js stride 128
  {
    int row = tid>>4, c0 = (tid&15)*8;
    const u16* sh = hin_hi + dir*1024 + (long)(b0+row)*2048;
    const u16* sl = hin_lo + dir*1024 + (long)(b0+row)*2048;
    #pragma unroll
    for (int j=0;j<8;j++){
      int c = c0 + j*128;
      *(int4*)&Ah[row][c] = *(const int4*)(sh + c);
      *(int4*)&Al[row][c] = *(const int4*)(sl + c);
    }
  }
  __syncthreads();

  const int g = w & 3;
  const int rh = (w >> 2) * 16;
  const int lane15 = lane & 15;
  const int cseg = (lane>>4)*8;
  const int rowb = g*1024 + u0 + lane15;
  const u16* bhp = Whh_hi + (long)rowb*1024 + cseg;
  const u16* blp = Whh_lo + (long)rowb*1024 + cseg;

  floatx4 accA = (floatx4)0.f, accB = (floatx4)0.f;
  #pragma unroll 4
  for (int kk=0; kk<32; kk+=2){
    int k0 = kk*32, k1 = k0 + 32;
    short8 bh0 = *(const short8*)(bhp + k0);
    short8 bl0 = *(const short8*)(blp + k0);
    short8 ah0 = *(const short8*)&Ah[rh + lane15][k0 + cseg];
    short8 al0 = *(const short8*)&Al[rh + lane15][k0 + cseg];
    accA = __builtin_amdgcn_mfma_f32_16x16x32_bf16(ah0, bh0, accA, 0,0,0);
    accA = __builtin_amdgcn_mfma_f32_16x16x32_bf16(al0, bh0, accA, 0,0,0);
    accA = __builtin_amdgcn_mfma_f32_16x16x32_bf16(ah0, bl0, accA, 0,0,0);
    short8 bh1 = *(const short8*)(bhp + k1);
    short8 bl1 = *(const short8*)(blp + k1);
    short8 ah1 = *(const short8*)&Ah[rh + lane15][k1 + cseg];
    short8 al1 = *(const short8*)&Al[rh + lane15][k1 + cseg];
    accB = __builtin_amdgcn_mfma_f32_16x16x32_bf16(ah1, bh1, accB, 0,0,0);
    accB = __builtin_amdgcn_mfma_f32_16x16x32_bf16(al1, bh1, accB, 0,0,0);
    accB = __builtin_amdgcn_mfma_f32_16x16x32_bf16(ah1, bl1, accB, 0,0,0);
  }
  floatx4 acc = accA + accB;
  const int rb0 = (lane>>4)*4;
  #pragma unroll
  for (int r=0;r<4;r++)
    gl[g][rh + rb0 + r][lane15] = acc[r];
  __syncthreads();
  {
    int bl_ = tid >> 4, u = tid & 15;      // 512 threads -> 32 rows x 16 u
    int b = b0 + bl_, uu = u0 + u;
    long grow = (long)(trow*64 + b)*8192 + dir*4096;
    float gi = gl[0][bl_][u] + Gfb[grow +        uu] + bias[uu];
    float gf = gl[1][bl_][u] + Gfb[grow + 1024 + uu] + bias[1024+uu];
    float gg2 = gl[2][bl_][u] + Gfb[grow + 2048 + uu] + bias[2048+uu];
    float go = gl[3][bl_][u] + Gfb[grow + 3072 + uu] + bias[3072+uu];
    float c_old = c_all[dir*65536 + b*1024 + uu];
    float c_new = sigm(gf)*c_old + sigm(gi)*tanhf(gg2);
    float h_new = sigm(go)*tanhf(c_new);
    bool valid = trow < src_len[b];
    if (valid) c_all[dir*65536 + b*1024 + uu] = c_new;
    u16 hh = f2bf(h_new);
    u16 hl = f2bf(h_new - bf2f(hh));
    int hidx = b*2048 + dir*1024 + uu;
    hout_hi[hidx] = valid ? hh : hin_hi[hidx];
    hout_lo[hidx] = valid ? hl : hin_lo[hidx];
    long eidx = (long)(b*50 + trow)*2048 + dir*1024 + uu;
    eo_hi[eidx] = valid ? hh : (u16)0;
    eo_lo[eidx] = valid ? hl : (u16)0;
  }
}

// ---------------- decoder gates step: 512-thread, staged A, K-half waves ---
// grid 256: b0 = (bx>>6)*16; u0 = (bx&63)*16.
// 8 waves (2/SIMD): wave = (gate g = w&3, K-half kh = w>>2).
// Dual chains per wave: critical path 192 -> 48 MFMAs.
__global__ __launch_bounds__(512) void dec_gates(
    int t,
    const u16* __restrict__ ain_hi, const u16* __restrict__ ain_lo,
    u16* __restrict__ aout_hi, u16* __restrict__ aout_lo,
    float* __restrict__ c_dec,
    const u16* __restrict__ Wcat_hi, const u16* __restrict__ Wcat_lo,
    const float* __restrict__ Gd,       // [3008][4096] f32
    const float* __restrict__ bias_d,
    float* __restrict__ hf32)           // [64][1024]
{
  __shared__ u16 Ah[16][2056], Al[16][2056];   // pad -> 2-way bank alias
  __shared__ float gl[8][16][17];
  const int tid=threadIdx.x, lane=tid&63, w=tid>>6;  // w 0..7
  const int b0 = (blockIdx.x >> 6) * 16;
  const int u0 = (blockIdx.x & 63) * 16;

  // stage A: 512 threads, row = tid>>5 (0..15), c0 = (tid&31)*8, 8 js stride 256
  {
    int row = tid>>5, c0 = (tid&31)*8;
    const u16* sh = ain_hi + (long)(b0+row)*2048;
    const u16* sl = ain_lo + (long)(b0+row)*2048;
    #pragma unroll
    for (int j=0;j<8;j++){
      int c = c0 + j*256;
      *(int4*)&Ah[row][c] = *(const int4*)(sh + c);
      *(int4*)&Al[row][c] = *(const int4*)(sl + c);
    }
  }
  __syncthreads();

  const int g = w & 3;
  const int kh = (w >> 2) * 1024;       // K-half elem offset
  const int lane15 = lane & 15;
  const int cseg = (lane>>4)*8;
  const int rowb = g*1024 + u0 + lane15;
  const u16* bhp = Wcat_hi + (long)rowb*2048 + kh + cseg;
  const u16* blp = Wcat_lo + (long)rowb*2048 + kh + cseg;

  floatx4 accA = (floatx4)0.f, accB = (floatx4)0.f;
  #pragma unroll 4
  for (int kk=0; kk<32; kk+=2){
    int k0 = kk*32, k1 = k0 + 32;
    short8 bh0 = *(const short8*)(bhp + k0);
    short8 bl0 = *(const short8*)(blp + k0);
    short8 ah0 = *(const short8*)&Ah[lane15][kh + k0 + cseg];
    short8 al0 = *(const short8*)&Al[lane15][kh + k0 + cseg];
    accA = __builtin_amdgcn_mfma_f32_16x16x32_bf16(ah0,bh0,accA,0,0,0);
    accA = __builtin_amdgcn_mfma_f32_16x16x32_bf16(al0,bh0,accA,0,0,0);
    accA = __builtin_amdgcn_mfma_f32_16x16x32_bf16(ah0,bl0,accA,0,0,0);
    short8 bh1 = *(const short8*)(bhp + k1);
    short8 bl1 = *(const short8*)(blp + k1);
    short8 ah1 = *(const short8*)&Ah[lane15][kh + k1 + cseg];
    short8 al1 = *(const short8*)&Al[lane15][kh + k1 + cseg];
    accB = __builtin_amdgcn_mfma_f32_16x16x32_bf16(ah1,bh1,accB,0,0,0);
    accB = __builtin_amdgcn_mfma_f32_16x16x32_bf16(al1,bh1,accB,0,0,0);
    accB = __builtin_amdgcn_mfma_f32_16x16x32_bf16(ah1,bl1,accB,0,0,0);
  }
  floatx4 acc = accA + accB;
  const int rb0=(lane>>4)*4;
  #pragma unroll
  for(int r=0;r<4;r++) gl[w][rb0+r][lane15] = acc[r];
  __syncthreads();
  if (tid < 256){
    int bl_ = tid>>4, u = tid&15;
    int b = b0 + bl_, uu = u0 + u;
    long grow = (long)(t*64 + b)*4096;
    float gi = gl[0][bl_][u] + gl[4][bl_][u] + Gd[grow +        uu] + bias_d[uu];
    float gf = gl[1][bl_][u] + gl[5][bl_][u] + Gd[grow + 1024 + uu] + bias_d[1024+uu];
    float gg2 = gl[2][bl_][u] + gl[6][bl_][u] + Gd[grow + 2048 + uu] + bias_d[2048+uu];
    float go = gl[3][bl_][u] + gl[7][bl_][u] + Gd[grow + 3072 + uu] + bias_d[3072+uu];
    float c_old = c_dec[b*1024+uu];
    float c_new = sigm(gf)*c_old + sigm(gi)*tanhf(gg2);
    float h_new = sigm(go)*tanhf(c_new);
    c_dec[b*1024+uu] = c_new;
    u16 hh = f2bf(h_new);
    u16 hl = f2bf(h_new - bf2f(hh));
    aout_hi[b*2048 + uu] = hh;  aout_lo[b*2048 + uu] = hl;
    hf32[b*1024 + uu] = h_new;
  }
}

// ---------------- attention scores+softmax (one block per batch) -----------
__global__ __launch_bounds__(256) void attn_w(
    const float* __restrict__ APf,          // [64*50][2048]: cols 0-1023 attnp
    const float* __restrict__ hf32,         // [64][1024]
    const int* __restrict__ src_len,
    float* __restrict__ wout)               // [64][50]
{
  __shared__ float h_sh[1024];
  __shared__ float sc_sh[50];
  const int tid = threadIdx.x, lane = tid&63, w = tid>>6;
  const int b = blockIdx.x;
  for (int i = tid; i < 1024; i += 256) h_sh[i] = hf32[b*1024 + i];
  __syncthreads();
  for (int tp = w; tp < 50; tp += 4){
    const float* ap = APf + (long)(b*50+tp)*2048;
    float p = 0.f;
    #pragma unroll
    for (int i=0;i<16;i++){ int d = lane + i*64; p += ap[d]*h_sh[d]; }
    #pragma unroll
    for (int off=32; off>0; off>>=1) p += __shfl_down(p, off);
    if (lane==0) sc_sh[tp] = p;
  }
  __syncthreads();
  if (w == 0){
    int len = src_len[b];
    float s = (lane < 50 && lane < len) ? sc_sh[lane] : -3.4e38f;
    float mx = s;
    #pragma unroll
    for (int off=32; off>0; off>>=1) mx = fmaxf(mx, __shfl_xor(mx, off));
    float p = (lane < 50 && lane < len) ? expf(s - mx) : 0.f;
    float sum = p;
    #pragma unroll
    for (int off=32; off>0; off>>=1) sum += __shfl_xor(sum, off);
    if (lane < 50) wout[b*50 + lane] = p / sum;
  }
}

// ---------------- dout step: dout = h@Wch^T + sum_tp w*P + bcomb -----------
// XCD-aware: b0 = ((bx>>6)&3)*16, n0 = (bx&63)*16. Waves split K=1024.
__global__ __launch_bounds__(256) void dout_step(
    int t,
    const u16* __restrict__ h_hi, const u16* __restrict__ h_lo,   // ac (h half), ld 2048
    const u16* __restrict__ Wch_h, const u16* __restrict__ Wch_l, // [1024][1024]
    const float* __restrict__ APf,      // [64*50][2048]: cols 1024+ = P
    const float* __restrict__ wout,     // [64][50]
    const float* __restrict__ bcomb,
    u16* __restrict__ ac_hi, u16* __restrict__ ac_lo,             // dout half out
    u16* __restrict__ dall_h)
{
  __shared__ u16 Ash[4][16][36], Asl[4][16][36];
  __shared__ u16 Bsh[4][16][36], Bsl[4][16][36];
  __shared__ float gl[4][16][17];
  const int tid=threadIdx.x, lane=tid&63, w=tid>>6;
  const int b0 = ((blockIdx.x >> 6) & 3) * 16;
  const int n0 = (blockIdx.x & 63) * 16;
  floatx4 acc = (floatx4)0.f;
  const int r = lane&15, sg = lane>>4;
  for (int kk=0; kk<8; kk++){
    int kb = w*256 + kk*32 + sg*8;
    *(int4*)&Ash[w][r][sg*8] = *(const int4*)(h_hi + (b0+r)*2048 + kb);
    *(int4*)&Asl[w][r][sg*8] = *(const int4*)(h_lo + (b0+r)*2048 + kb);
    *(int4*)&Bsh[w][r][sg*8] = *(const int4*)(Wch_h + (long)(n0+r)*1024 + kb);
    *(int4*)&Bsl[w][r][sg*8] = *(const int4*)(Wch_l + (long)(n0+r)*1024 + kb);
    __syncthreads();
    short8 ah = *(const short8*)&Ash[w][lane&15][(lane>>4)*8];
    short8 al = *(const short8*)&Asl[w][lane&15][(lane>>4)*8];
    short8 bh = *(const short8*)&Bsh[w][lane&15][(lane>>4)*8];
    short8 bl = *(const short8*)&Bsl[w][lane&15][(lane>>4)*8];
    acc = __builtin_amdgcn_mfma_f32_16x16x32_bf16(ah,bh,acc,0,0,0);
    acc = __builtin_amdgcn_mfma_f32_16x16x32_bf16(al,bh,acc,0,0,0);
    acc = __builtin_amdgcn_mfma_f32_16x16x32_bf16(ah,bl,acc,0,0,0);
    __syncthreads();
  }
  const int rb0=(lane>>4)*4, cf=lane&15;
  #pragma unroll
  for(int rr=0;rr<4;rr++) gl[w][rb0+rr][cf] = acc[rr];
  __syncthreads();
  {
    int bl_ = tid>>4, nl = tid&15;
    int b = b0 + bl_, nn = n0 + nl;
    float v = gl[0][bl_][nl]+gl[1][bl_][nl]+gl[2][bl_][nl]+gl[3][bl_][nl] + bcomb[nn];
    const float* wp = wout + b*50;
    const float* Pp = APf + (long)(b*50)*2048 + 1024 + nn;
    for (int tp=0; tp<50; tp++) v += wp[tp] * Pp[(long)tp*2048];
    u16 h = f2bf(v), l = f2bf(v - bf2f(h));
    ac_hi[b*2048 + 1024 + nn] = h;  ac_lo[b*2048 + 1024 + nn] = l;
    float rv = v > 0.f ? v : 0.f;
    dall_h[(long)(b*47 + t)*1024 + nn] = f2bf(rv);
  }
}

// ---------------- logits: out_b[v][t] = Wout @ dall_b^T + bout -------------
// XCD-partitioned grid (8, 512): x = XCD slot; y = vtile-local*32 + bpair.
// 2 batch elements per block.
__global__ __launch_bounds__(256) void logits_gemm(
    const u16* __restrict__ Wout_bf,                // [32000][1024]
    const u16* __restrict__ dall_h,                 // [3009][1024]
    const float* __restrict__ bout,
    float* __restrict__ out)                        // [64][32000][47]
{
  const int x = blockIdx.x;                 // 0..7
  const int y = blockIdx.y;                 // 0..511
  const int cnt = (x < 5) ? 16 : 15;        // vtiles for this XCD (125 total)
  if (y >= cnt*32) return;
  const int vt = ((x < 5) ? x*16 : 80 + (x-5)*15) + (y >> 5);
  const int b0 = (y & 31)*2;
  const int v0 = vt * 256;

  __shared__ u16 Wsh[256][36];
  __shared__ u16 Dh[2][48][36];
  const int tid = threadIdx.x, lane = tid&63, w = tid>>6;
  floatx4 acc[2][4][3];
  #pragma unroll
  for (int bb=0;bb<2;bb++)
    #pragma unroll
    for (int i=0;i<4;i++)
      #pragma unroll
      for (int j=0;j<3;j++) acc[bb][i][j]=(floatx4)0.f;
  const int lrow = tid>>1, lseg = tid&1;
  for (int kk=0; kk<32; kk++){
    int kb = kk*32;
    #pragma unroll
    for (int p=0;p<2;p++){
      int row = lrow + p*128;
      const u16* src = Wout_bf + (long)(v0+row)*1024 + kb + lseg*16;
      *(int4*)&Wsh[row][lseg*16]     = *(const int4*)(src);
      *(int4*)&Wsh[row][lseg*16 + 8] = *(const int4*)(src + 8);
    }
    if (tid < 192){
      int bb = tid/96, t2 = tid - bb*96;
      int row = t2>>1, sg = t2&1;
      long a = (long)((b0+bb)*47+row)*1024 + kb + sg*16;
      *(int4*)&Dh[bb][row][sg*16]     = *(const int4*)(dall_h + a);
      *(int4*)&Dh[bb][row][sg*16 + 8] = *(const int4*)(dall_h + a + 8);
    }
    __syncthreads();
    short8 av[4];
    #pragma unroll
    for (int i=0;i<4;i++)
      av[i] = *(const short8*)&Wsh[w*64 + i*16 + (lane&15)][(lane>>4)*8];
    #pragma unroll
    for (int j=0;j<3;j++){
      #pragma unroll
      for (int bb=0;bb<2;bb++){
        short8 bh = *(const short8*)&Dh[bb][j*16 + (lane&15)][(lane>>4)*8];
        #pragma unroll
        for (int i=0;i<4;i++)
          acc[bb][i][j] = __builtin_amdgcn_mfma_f32_16x16x32_bf16(av[i], bh, acc[bb][i][j], 0,0,0);
      }
    }
    __syncthreads();
  }
  const int rb0=(lane>>4)*4, cf=lane&15;
  #pragma unroll
  for (int bb=0;bb<2;bb++){
    #pragma unroll
    for (int i=0;i<4;i++){
      #pragma unroll
      for (int j=0;j<3;j++){
        int tt = j*16 + cf;
        if (tt >= 47) continue;
        #pragma unroll
        for (int r=0;r<4;r++){
          int v = v0 + w*64 + i*16 + rb0 + r;
          out[(long)(b0+bb)*1504000 + (long)v*47 + tt] = acc[bb][i][j][r] + bout[v];
        }
      }
    }
  }
}

// ===========================================================================
extern "C" void kernel_launch(void* const* d_in, const int* in_sizes, int n_in,
                              void* d_out, int out_size, void* d_ws, size_t ws_size,
                              hipStream_t stream)
{
  (void)in_sizes; (void)n_in; (void)out_size; (void)ws_size;
  const int*   src     = (const int*)d_in[0];
  const int*   src_len = (const int*)d_in[1];
  const int*   trg     = (const int*)d_in[2];
  const float* enc_emb = (const float*)d_in[3];
  const float* Wih_f   = (const float*)d_in[4];
  const float* Whh_f   = (const float*)d_in[5];
  const float* bih_f   = (const float*)d_in[6];
  const float* bhh_f   = (const float*)d_in[7];
  const float* Wih_b   = (const float*)d_in[8];
  const float* Whh_b   = (const float*)d_in[9];
  const float* bih_b   = (const float*)d_in[10];
  const float* bhh_b   = (const float*)d_in[11];
  const float* Wfch    = (const float*)d_in[12];
  const float* bfch    = (const float*)d_in[13];
  const float* Wfcc    = (const float*)d_in[14];
  const float* bfcc    = (const float*)d_in[15];
  const float* dec_emb = (const float*)d_in[16];
  const float* Wih_d   = (const float*)d_in[17];
  const float* Whh_d   = (const float*)d_in[18];
  const float* bih_d   = (const float*)d_in[19];
  const float* bhh_d   = (const float*)d_in[20];
  const float* Wattn   = (const float*)d_in[21];
  const float* battn   = (const float*)d_in[22];
  const float* Wcomb   = (const float*)d_in[23];
  const float* bcomb   = (const float*)d_in[24];
  const float* Wout    = (const float*)d_in[25];
  const float* bout    = (const float*)d_in[26];
  float* out = (float*)d_out;

  size_t off = 0;
  auto alloc = [&](size_t bytes)->void*{
    void* p = (char*)d_ws + off; off += (bytes + 255) & ~(size_t)255; return p; };

  // combined encoder input-proj weights: rows 0-4095 Wih_f, 4096-8191 Wih_b
  u16* Wenc_h = (u16*)alloc((size_t)8192*1024*2);  u16* Wenc_l = (u16*)alloc((size_t)8192*1024*2);
  u16* Whhf_h = (u16*)alloc((size_t)4096*1024*2);  u16* Whhf_l = (u16*)alloc((size_t)4096*1024*2);
  u16* Whhb_h = (u16*)alloc((size_t)4096*1024*2);  u16* Whhb_l = (u16*)alloc((size_t)4096*1024*2);
  u16* WihdA_h= (u16*)alloc((size_t)4096*1024*2);  u16* WihdA_l= (u16*)alloc((size_t)4096*1024*2);
  u16* Wcat_h = (u16*)alloc((size_t)4096*2048*2);  u16* Wcat_l = (u16*)alloc((size_t)4096*2048*2);
  u16* Wfch_h = (u16*)alloc((size_t)1024*2048*2);  u16* Wfch_l = (u16*)alloc((size_t)1024*2048*2);
  u16* Wfcc_h = (u16*)alloc((size_t)1024*2048*2);  u16* Wfcc_l = (u16*)alloc((size_t)1024*2048*2);
  // combined attn/P weights: rows 0-1023 Wattn, 1024-2047 Wcomb[:, :2048]
  u16* Wap_h  = (u16*)alloc((size_t)2048*2048*2);  u16* Wap_l  = (u16*)alloc((size_t)2048*2048*2);
  u16* Wch_h  = (u16*)alloc((size_t)1024*1024*2);  u16* Wch_l  = (u16*)alloc((size_t)1024*1024*2);
  u16* Wout_bf =(u16*)alloc((size_t)32000*1024*2);
  u16* embx_h = (u16*)alloc((size_t)3200*1024*2);  u16* embx_l = (u16*)alloc((size_t)3200*1024*2);
  u16* dembx_h= (u16*)alloc((size_t)3008*1024*2);  u16* dembx_l= (u16*)alloc((size_t)3008*1024*2);
  float* Gfb  = (float*)alloc((size_t)3200*8192*4);
  float* Gd   = (float*)alloc((size_t)3008*4096*4);
  u16* eo_h  = (u16*)alloc((size_t)3200*2048*2);
  u16* eo_l  = (u16*)alloc((size_t)3200*2048*2);
  u16* h0_h  = (u16*)alloc((size_t)64*2048*2);  u16* h0_l  = (u16*)alloc((size_t)64*2048*2);
  u16* h1_h  = (u16*)alloc((size_t)64*2048*2);  u16* h1_l  = (u16*)alloc((size_t)64*2048*2);
  u16* cfin_h= (u16*)alloc((size_t)64*2048*2);  u16* cfin_l= (u16*)alloc((size_t)64*2048*2);
  u16* ac0_h = (u16*)alloc((size_t)64*2048*2);  u16* ac0_l = (u16*)alloc((size_t)64*2048*2);
  u16* ac1_h = (u16*)alloc((size_t)64*2048*2);  u16* ac1_l = (u16*)alloc((size_t)64*2048*2);
  u16* dall_h= (u16*)alloc((size_t)3009*1024*2);
  float* APf   = (float*)alloc((size_t)3200*2048*4);
  float* c_enc = (float*)alloc((size_t)2*64*1024*4);
  float* c_dec = (float*)alloc((size_t)64*1024*4);
  float* hf32  = (float*)alloc((size_t)64*1024*4);
  float* wout  = (float*)alloc((size_t)64*50*4);
  float* bias_f = (float*)alloc(4096*4);
  float* bias_b = (float*)alloc(4096*4);
  float* bias_d = (float*)alloc(4096*4);
  float* bias_ap= (float*)alloc(2048*4);

  // --- weight conversion (fused families) ---
  cvtA<<<dim3(4096,1,4),256,0,stream>>>(Wih_f, Wih_b, Whh_f, Whh_b,
                                        Wenc_h, Wenc_h + (size_t)4096*1024, Whhf_h, Whhb_h,
                                        Wenc_l, Wenc_l + (size_t)4096*1024, Whhf_l, Whhb_l);
  cvtB<<<dim3(1024,2,4),256,0,stream>>>(Wfch, 2048, Wfcc, 2048, Wattn, 2048, Wcomb, 3072,
                                        Wfch_h, Wfcc_h, Wap_h, Wap_h + (size_t)1024*2048,
                                        Wfch_l, Wfcc_l, Wap_l, Wap_l + (size_t)1024*2048);
  cvtC<<<dim3(4096,1,3),256,0,stream>>>(Wih_d, 2048, WihdA_h, WihdA_l, 1024,
                                        Whh_d, 1024, Wcat_h, Wcat_l, 2048,
                                        Wih_d + 1024, 2048, Wcat_h + 1024, Wcat_l + 1024, 2048);
  cvtC<<<dim3(1024,1,1),256,0,stream>>>(Wcomb + 2048, 3072, Wch_h, Wch_l, 1024,
                                        Wcomb + 2048, 3072, Wch_h, Wch_l, 1024,
                                        Wcomb + 2048, 3072, Wch_h, Wch_l, 1024);
  cvt2d<<<dim3(32000,1),256,0,stream>>>(Wout, 1024, Wout_bf, 1024, 1024);
  bias_combine<<<16,256,0,stream>>>(bih_f,bhh_f,bias_f, bih_b,bhh_b,bias_b, bih_d,bhh_d,bias_d, battn,bias_ap);

  // --- embedding gathers (split) ---
  gather_embed_split<<<3200,256,0,stream>>>(src, enc_emb, embx_h, embx_l);
  gather_embed_split<<<3008,256,0,stream>>>(trg, dec_emb, dembx_h, dembx_l);

  // --- zero-init recurrent state ---
  zero_u32<<<256,256,0,stream>>>((unsigned int*)h0_h, 65536);
  zero_u32<<<256,256,0,stream>>>((unsigned int*)h0_l, 65536);
  zero_u32<<<256,256,0,stream>>>((unsigned int*)ac0_h, 65536);
  zero_u32<<<256,256,0,stream>>>((unsigned int*)ac0_l, 65536);
  zero_u32<<<512,256,0,stream>>>((unsigned int*)c_enc, 131072);

  // --- input projections (3-pass split, bias-free, f32 out) ---
  gemm128<1,1><<<dim3(25,64),256,0,stream>>>(embx_h, embx_l, 1024, Wenc_h, Wenc_l, 1024, 3200, 8192, 1024, nullptr, Gfb, 8192);
  gemm128<1,1><<<dim3(24,32),256,0,stream>>>(dembx_h, dembx_l, 1024, WihdA_h, WihdA_l, 1024, 3008, 4096, 1024, nullptr, Gd, 4096);

  // --- encoder scan (per-step launches, 512-thread blocks) ---
  u16* hh_[2] = {h0_h, h1_h};
  u16* hl_[2] = {h0_l, h1_l};
  for (int s=0; s<50; s++)
    enc_step<<<256,512,0,stream>>>(s, hh_[s&1], hl_[s&1], hh_[(s+1)&1], hl_[(s+1)&1], c_enc,
                                   Whhf_h, Whhf_l, Whhb_h, Whhb_l, Gfb, bias_f, bias_b, src_len, eo_h, eo_l);

  // --- final cell states -> split bf16 ---
  cvt_cell_split<<<64,256,0,stream>>>(c_enc, cfin_h, cfin_l);

  // --- combined attn_proj + P (f32 out, ld 2048) ---
  gemm128<1,1><<<dim3(25,16),256,0,stream>>>(eo_h, eo_l, 2048, Wap_h, Wap_l, 2048, 3200, 2048, 2048, bias_ap, APf, 2048);

  // --- decoder init ---
  gemm64<0><<<16,256,0,stream>>>(h0_h, h0_l, 2048, Wfch_h, Wfch_l, 2048, 2048, bfch, nullptr, ac0_h, ac0_l);
  gemm64<1><<<16,256,0,stream>>>(cfin_h, cfin_l, 2048, Wfcc_h, Wfcc_l, 2048, 2048, bfcc, c_dec, nullptr, nullptr);

  // --- decoder scan (per-step launches) ---
  u16* ah_[2] = {ac0_h, ac1_h};
  u16* al_[2] = {ac0_l, ac1_l};
  for (int t=0; t<47; t++){
    int cur = t&1, nxt = (t+1)&1;
    dec_gates<<<256,512,0,stream>>>(t, ah_[cur], al_[cur], ah_[nxt], al_[nxt], c_dec,
                                    Wcat_h, Wcat_l, Gd, bias_d, hf32);
    attn_w<<<64,256,0,stream>>>(APf, hf32, src_len, wout);
    dout_step<<<256,256,0,stream>>>(t, ah_[nxt], al_[nxt], Wch_h, Wch_l, APf, wout, bcomb,
                                    ah_[nxt], al_[nxt], dall_h);
  }

  // --- output projection, XCD-partitioned, 2 b per block ---
  logits_gemm<<<dim3(8,512),256,0,stream>>>(Wout_bf, dall_h, bout, out);
}